// Round 1
// baseline (466.234 us; speedup 1.0000x reference)
//
#include <hip/hip_runtime.h>

// Problem constants
#define HH 28
#define WW 28
#define DIMC 384          // C
#define LL 785            // 1 + 28*28
#define FDIM 1536         // 4*C  (GEMM K)
#define ODIM 768          // 2*C  (GEMM N)
#define NPATCH 196        // 14*14
#define MROWS 12544       // B*196 (GEMM M)
#define BATCH 64

typedef __attribute__((ext_vector_type(8))) short bf16x8;
typedef __attribute__((ext_vector_type(4))) float floatx4;
typedef __attribute__((ext_vector_type(4))) unsigned short ushort4v;

__device__ __forceinline__ unsigned short f2bf(float f) {
  union { float f; unsigned int u; } v; v.f = f;
  unsigned int u = v.u + 0x7fffu + ((v.u >> 16) & 1u);   // RNE
  return (unsigned short)(u >> 16);
}

// ---------------------------------------------------------------------------
// Kernel 1: per-m-row mean / rsqrt(var+eps). One wave (64 lanes) per row.
// Row r = b*196 + (i*14+j); element f -> quadrant q=f/384, channel c=f%384,
// source x[b, 1 + (2i+(q&1))*28 + (2j+((q>>1)&1)), c].
// ---------------------------------------------------------------------------
__global__ __launch_bounds__(256) void stats_kernel(const float* __restrict__ x,
                                                    float* __restrict__ stats) {
  int gw = (blockIdx.x * 256 + threadIdx.x) >> 6;
  int lane = threadIdx.x & 63;
  if (gw >= MROWS) return;
  int b = gw / NPATCH;
  int n = gw - b * NPATCH;
  int i = n / 14;
  int j = n - i * 14;
  const float* xb = x + ((size_t)b * LL + 1) * DIMC;
  float s = 0.f, s2 = 0.f;
#pragma unroll
  for (int tch = 0; tch < 6; ++tch) {
    int f = lane * 4 + tch * 256;          // 384%4==0 -> float4 never crosses q
    int q = f / 384;
    int c = f - q * 384;
    int off = ((i * 2 + (q & 1)) * WW + (j * 2 + ((q >> 1) & 1))) * DIMC + c;
    float4 v = *reinterpret_cast<const float4*>(xb + off);
    s  += v.x + v.y + v.z + v.w;
    s2 += v.x * v.x + v.y * v.y + v.z * v.z + v.w * v.w;
  }
#pragma unroll
  for (int o = 32; o > 0; o >>= 1) {
    s  += __shfl_down(s, o);
    s2 += __shfl_down(s2, o);
  }
  if (lane == 0) {
    float mu = s * (1.f / FDIM);
    float var = s2 * (1.f / FDIM) - mu * mu;
    stats[2 * gw]     = mu;
    stats[2 * gw + 1] = rsqrtf(var + 1e-5f);
  }
}

// ---------------------------------------------------------------------------
// Kernel 2: fused gather+LayerNorm+GEMM.
//   out[b, 1+n, o] = sum_f norm(m[b,n,f]) * w_red[o,f]
// Tile: BM=128 (grid.y=98), BN=128 (grid.x=6), BK=64, 256 threads = 4 waves.
// Wave (wv>>1, wv&1) owns a 64x64 sub-tile = 4x4 of 16x16x32 bf16 MFMA.
// LDS row stride 72 (144 B): row-to-row bank shift 4 -> only free 2-way
// conflicts on ds_read_b128.
// ---------------------------------------------------------------------------
__global__ __launch_bounds__(256) void gemm_kernel(
    const float* __restrict__ x, const float* __restrict__ wred,
    const float* __restrict__ gamma, const float* __restrict__ beta,
    const float* __restrict__ stats, float* __restrict__ out) {
  __shared__ unsigned short As[128][72];
  __shared__ unsigned short Bs[128][72];

  const int t = threadIdx.x;
  const int cz = t & 15;         // 4-float column chunk within BK=64
  const int rsub = t >> 4;       // 0..15; pass p covers rows p*16+rsub
  const int col4 = cz * 4;

  // Hoist per-row address math + LN stats out of the K loop (32-bit offsets:
  // x has 19.3M elements, wred 1.18M -> fits u32).
  unsigned int xoff[8], woff[8];
  float mus[8], rss[8];
#pragma unroll
  for (int p = 0; p < 8; ++p) {
    int row = p * 16 + rsub;
    int m_idx = blockIdx.y * 128 + row;
    int b = m_idx / NPATCH;
    int n = m_idx - b * NPATCH;
    int i = n / 14;
    int j = n - i * 14;
    xoff[p] = ((unsigned)b * LL + 1) * DIMC + (unsigned)(i * 2 * WW + j * 2) * DIMC;
    mus[p] = stats[2 * m_idx];
    rss[p] = stats[2 * m_idx + 1];
    woff[p] = (unsigned)(blockIdx.x * 128 + row) * FDIM + col4;
  }

  const int wv = t >> 6;
  const int lane = t & 63;
  const int ln15 = lane & 15;
  const int quad = lane >> 4;
  const int aRow = (wv >> 1) * 64 + ln15;
  const int bCol = (wv & 1) * 64 + ln15;

  floatx4 acc[4][4];
#pragma unroll
  for (int mt = 0; mt < 4; ++mt)
#pragma unroll
    for (int nt = 0; nt < 4; ++nt)
      acc[mt][nt] = floatx4{0.f, 0.f, 0.f, 0.f};

  for (int kt = 0; kt < FDIM / 64; ++kt) {
    const int k0 = kt * 64;
    const int q = k0 / 384;                 // 384 = 6*64: BK slice never crosses q
    const int cb = k0 - q * 384 + col4;
    const int qoff = ((q & 1) * WW + ((q >> 1) & 1)) * DIMC;

    float4 av[8], bv[8];
#pragma unroll
    for (int p = 0; p < 8; ++p)
      av[p] = *reinterpret_cast<const float4*>(x + xoff[p] + qoff + cb);
#pragma unroll
    for (int p = 0; p < 8; ++p)
      bv[p] = *reinterpret_cast<const float4*>(wred + woff[p] + k0);
    float4 g4  = *reinterpret_cast<const float4*>(gamma + k0 + col4);
    float4 be4 = *reinterpret_cast<const float4*>(beta + k0 + col4);

    __syncthreads();   // previous iteration's LDS reads done
#pragma unroll
    for (int p = 0; p < 8; ++p) {
      int row = p * 16 + rsub;
      float4 v = av[p];
      ushort4v ua;
      ua.x = f2bf((v.x - mus[p]) * rss[p] * g4.x + be4.x);
      ua.y = f2bf((v.y - mus[p]) * rss[p] * g4.y + be4.y);
      ua.z = f2bf((v.z - mus[p]) * rss[p] * g4.z + be4.z);
      ua.w = f2bf((v.w - mus[p]) * rss[p] * g4.w + be4.w);
      *reinterpret_cast<ushort4v*>(&As[row][col4]) = ua;
      float4 w = bv[p];
      ushort4v ub;
      ub.x = f2bf(w.x); ub.y = f2bf(w.y); ub.z = f2bf(w.z); ub.w = f2bf(w.w);
      *reinterpret_cast<ushort4v*>(&Bs[row][col4]) = ub;
    }
    __syncthreads();   // tile staged

#pragma unroll
    for (int ks = 0; ks < 64; ks += 32) {
      bf16x8 af[4], bfr[4];
#pragma unroll
      for (int mt = 0; mt < 4; ++mt)
        af[mt] = *reinterpret_cast<const bf16x8*>(&As[aRow + mt * 16][ks + quad * 8]);
#pragma unroll
      for (int nt = 0; nt < 4; ++nt)
        bfr[nt] = *reinterpret_cast<const bf16x8*>(&Bs[bCol + nt * 16][ks + quad * 8]);
#pragma unroll
      for (int mt = 0; mt < 4; ++mt)
#pragma unroll
        for (int nt = 0; nt < 4; ++nt)
          acc[mt][nt] = __builtin_amdgcn_mfma_f32_16x16x32_bf16(af[mt], bfr[nt],
                                                                acc[mt][nt], 0, 0, 0);
    }
  }

  // Epilogue. C/D layout: col = lane&15, row = quad*4 + reg  [measured m89/m91].
  const int colBase = blockIdx.x * 128 + (wv & 1) * 64;
  const int rowBase = blockIdx.y * 128 + (wv >> 1) * 64;
#pragma unroll
  for (int mt = 0; mt < 4; ++mt) {
#pragma unroll
    for (int r = 0; r < 4; ++r) {
      int m_idx = rowBase + mt * 16 + quad * 4 + r;
      int b = m_idx / NPATCH;
      int n = m_idx - b * NPATCH;
      float* orow = out + ((size_t)b * 197 + 1 + n) * ODIM;
#pragma unroll
      for (int nt = 0; nt < 4; ++nt)
        orow[colBase + nt * 16 + ln15] = acc[mt][nt][r];
    }
  }
}

// ---------------------------------------------------------------------------
// Kernel 3: cls token: out[b,0,o] = dot(x[b,0,:], w_convert[o,:]) (fp32).
// ---------------------------------------------------------------------------
__global__ __launch_bounds__(256) void cls_kernel(const float* __restrict__ x,
                                                  const float* __restrict__ wc,
                                                  float* __restrict__ out) {
  __shared__ float xs[DIMC];
  int b = blockIdx.x;
  int t = threadIdx.x;
  for (int c = t; c < DIMC; c += 256) xs[c] = x[(size_t)b * LL * DIMC + c];
  __syncthreads();
  for (int o = t; o < ODIM; o += 256) {
    const float* wr = wc + (size_t)o * DIMC;
    float acc = 0.f;
#pragma unroll 4
    for (int c = 0; c < DIMC; c += 4) {
      float4 wv = *reinterpret_cast<const float4*>(wr + c);
      acc += wv.x * xs[c] + wv.y * xs[c + 1] + wv.z * xs[c + 2] + wv.w * xs[c + 3];
    }
    out[(size_t)b * 197 * ODIM + o] = acc;
  }
}

extern "C" void kernel_launch(void* const* d_in, const int* in_sizes, int n_in,
                              void* d_out, int out_size, void* d_ws, size_t ws_size,
                              hipStream_t stream) {
  const float* x     = (const float*)d_in[0];   // (64, 785, 384)
  const float* wred  = (const float*)d_in[1];   // (768, 1536)
  const float* wconv = (const float*)d_in[2];   // (768, 384)
  const float* gamma = (const float*)d_in[3];   // (1536,)
  const float* beta  = (const float*)d_in[4];   // (1536,)
  float* out = (float*)d_out;                   // (64, 197, 768)
  float* stats = (float*)d_ws;                  // (12544, 2) -> 100 KB

  stats_kernel<<<dim3(MROWS / 4), 256, 0, stream>>>(x, stats);
  gemm_kernel<<<dim3(ODIM / 128, MROWS / 128), 256, 0, stream>>>(
      x, wred, gamma, beta, stats, out);
  cls_kernel<<<dim3(BATCH), 256, 0, stream>>>(x, wconv, out);
}

// Round 2
// 366.003 us; speedup vs baseline: 1.2739x; 1.2739x over previous
//
#include <hip/hip_runtime.h>
#include <hip/hip_bf16.h>

#define DIMC 384          // C
#define LL 785            // 1 + 28*28
#define FDIM 1536         // 4*C  (GEMM K)
#define ODIM 768          // 2*C  (GEMM N)
#define NPATCH 196        // 14*14
#define MROWS 12544       // B*196 (GEMM M)
#define BATCH 64

typedef __attribute__((ext_vector_type(8))) short bf16x8;
typedef __attribute__((ext_vector_type(4))) float floatx4;
typedef __attribute__((ext_vector_type(4))) unsigned short ushort4v;

// ws layout (bytes): stats f32[2*12544] @0 ; wbf u16[768*1536] @100352 ;
// bias f32[768] @2459648.  Total 2462720 B (~2.35 MB).
#define WS_WBF_OFF  100352
#define WS_BIAS_OFF 2459648

__device__ __forceinline__ unsigned short f2bf(float f) {
  union { float f; unsigned int u; } v; v.f = f;
  unsigned int u = v.u + 0x7fffu + ((v.u >> 16) & 1u);   // RNE
  return (unsigned short)(u >> 16);
}

// pack 8 fp32 (already loaded) -> bf16x8 applying val*s + b, RNE
__device__ __forceinline__ bf16x8 pack8(float4 lo, float4 hi, float s, float b) {
  union { bf16x8 v; __hip_bfloat162 h[4]; } u;
  u.h[0] = __float22bfloat162_rn(make_float2(lo.x * s + b, lo.y * s + b));
  u.h[1] = __float22bfloat162_rn(make_float2(lo.z * s + b, lo.w * s + b));
  u.h[2] = __float22bfloat162_rn(make_float2(hi.x * s + b, hi.y * s + b));
  u.h[3] = __float22bfloat162_rn(make_float2(hi.z * s + b, hi.w * s + b));
  return u.v;
}

// ---------------------------------------------------------------------------
// Prep kernel: one launch, blocks partitioned by role.
//  [0,3136)      stats: one wave per m-row -> mu, rsqrt(var+eps)
//  [3136,4288)   wbf:   wbf[o][f] = bf16(gamma[f] * w_red[o][f])
//  [4288,4480)   bias:  bias[o] = sum_f beta[f] * w_red[o][f]
//  [4480,4672)   cls:   out[b,0,o] = dot(x[b,0,:], w_conv[o,:])
// ---------------------------------------------------------------------------
__global__ __launch_bounds__(256) void prep_kernel(
    const float* __restrict__ x, const float* __restrict__ wred,
    const float* __restrict__ wconv, const float* __restrict__ gamma,
    const float* __restrict__ beta, float* __restrict__ stats,
    unsigned short* __restrict__ wbf, float* __restrict__ bias,
    float* __restrict__ out) {
  const int blk = blockIdx.x;
  const int t = threadIdx.x;
  const int wv = t >> 6;
  const int lane = t & 63;

  if (blk < 3136) {                      // ---- stats ----
    int gw = blk * 4 + wv;               // m-row
    int b = gw / NPATCH;
    int n = gw - b * NPATCH;
    int i = n / 14;
    int j = n - i * 14;
    const float* xb = x + ((size_t)b * LL + 1) * DIMC;
    float s = 0.f, s2 = 0.f;
#pragma unroll
    for (int c = 0; c < 6; ++c) {
      int f = lane * 4 + c * 256;        // 384%4==0: float4 never crosses q
      int q = f / 384;
      int cc = f - q * 384;
      int off = ((i * 2 + (q & 1)) * 28 + (j * 2 + ((q >> 1) & 1))) * DIMC + cc;
      float4 v = *reinterpret_cast<const float4*>(xb + off);
      s  += v.x + v.y + v.z + v.w;
      s2 += v.x * v.x + v.y * v.y + v.z * v.z + v.w * v.w;
    }
#pragma unroll
    for (int o = 32; o > 0; o >>= 1) {
      s  += __shfl_down(s, o);
      s2 += __shfl_down(s2, o);
    }
    if (lane == 0) {
      float mu = s * (1.f / FDIM);
      float var = s2 * (1.f / FDIM) - mu * mu;
      stats[2 * gw]     = mu;
      stats[2 * gw + 1] = rsqrtf(var + 1e-5f);
    }
  } else if (blk < 4288) {               // ---- wbf = bf16(gamma * w_red) ----
    int idx4 = (blk - 3136) * 256 + t;   // < 294912
    int e0 = idx4 * 4;
    int f = e0 % FDIM;                   // float4 stays in-row (1536%4==0)
    float4 w = *reinterpret_cast<const float4*>(wred + e0);
    float4 g = *reinterpret_cast<const float4*>(gamma + f);
    ushort4v u;
    u.x = f2bf(w.x * g.x); u.y = f2bf(w.y * g.y);
    u.z = f2bf(w.z * g.z); u.w = f2bf(w.w * g.w);
    *reinterpret_cast<ushort4v*>(wbf + e0) = u;
  } else if (blk < 4480) {               // ---- bias ----
    int o = (blk - 4288) * 4 + wv;       // < 768
    const float* wr = wred + (size_t)o * FDIM;
    float s = 0.f;
#pragma unroll
    for (int c = 0; c < 6; ++c) {
      int f = lane * 4 + c * 256;
      float4 w = *reinterpret_cast<const float4*>(wr + f);
      float4 be = *reinterpret_cast<const float4*>(beta + f);
      s += w.x * be.x + w.y * be.y + w.z * be.z + w.w * be.w;
    }
#pragma unroll
    for (int o2 = 32; o2 > 0; o2 >>= 1) s += __shfl_down(s, o2);
    if (lane == 0) bias[o] = s;
  } else {                               // ---- cls ----
    __shared__ float xs[DIMC];
    int idx = blk - 4480;                // < 192
    int b = idx / 3;
    int ch = idx - b * 3;
    for (int c = t; c < DIMC; c += 256) xs[c] = x[(size_t)b * LL * DIMC + c];
    __syncthreads();
    int o = ch * 256 + t;
    const float* wr = wconv + (size_t)o * DIMC;
    float acc = 0.f;
#pragma unroll 4
    for (int c = 0; c < DIMC; c += 4) {
      float4 w = *reinterpret_cast<const float4*>(wr + c);
      acc += w.x * xs[c] + w.y * xs[c + 1] + w.z * xs[c + 2] + w.w * xs[c + 3];
    }
    out[(size_t)b * 197 * ODIM + o] = acc;
  }
}

// ---------------------------------------------------------------------------
// GEMM: no LDS, no barriers. One wave = 32x128 output tile (2 x 8 MFMA tiles
// of 16x16, K accumulated over 1536 with 16x16x32 bf16 MFMA).
// A fragments built in-register from gathered x + LayerNorm (1 fma/elem:
// t = v*rs - mu*rs; gamma folded into B, beta folded into bias).
// B fragments read directly from pre-converted bf16 weights (L2-resident).
// 2352 waves = 588 blocks -> all co-resident, latency hidden by TLP+ILP.
// ---------------------------------------------------------------------------
__global__ __launch_bounds__(256) void gemm_kernel(
    const float* __restrict__ x, const unsigned short* __restrict__ wbf,
    const float* __restrict__ stats, const float* __restrict__ bias,
    float* __restrict__ out) {
  const int t = threadIdx.x;
  const int wv = t >> 6;
  const int lane = t & 63;
  const int ln15 = lane & 15;
  const int quad = lane >> 4;
  const int gw = blockIdx.x * 4 + wv;        // 0..2351
  const int rowBlk = gw / 6;                 // 0..391
  const int colBlk = gw - rowBlk * 6;        // 0..5
  const int rbase = rowBlk * 32;
  const int cbase = colBlk * 128;

  // Per-row (mt) gather offsets + folded LN coefficients.
  unsigned int xoff[2];
  float rs[2], nmu[2];
#pragma unroll
  for (int mt = 0; mt < 2; ++mt) {
    int m = rbase + mt * 16 + ln15;
    int b = m / NPATCH;
    int n = m - b * NPATCH;
    int i = n / 14;
    int j = n - i * 14;
    xoff[mt] = ((unsigned)b * LL + 1) * DIMC + (unsigned)(i * 2 * 28 + j * 2) * DIMC;
    float mu = stats[2 * m];
    float r  = stats[2 * m + 1];
    rs[mt]  = r;
    nmu[mt] = -mu * r;                       // t = v*rs + nmu
  }
  unsigned int boff[8];
#pragma unroll
  for (int nt = 0; nt < 8; ++nt)
    boff[nt] = (unsigned)(cbase + nt * 16 + ln15) * FDIM;

  floatx4 acc[2][8];
#pragma unroll
  for (int mt = 0; mt < 2; ++mt)
#pragma unroll
    for (int nt = 0; nt < 8; ++nt)
      acc[mt][nt] = floatx4{0.f, 0.f, 0.f, 0.f};

  for (int kt = 0; kt < FDIM / 64; ++kt) {
    const int k0 = kt * 64;
    const int q = k0 / DIMC;                 // constant over a 64-slice
    const int cb = k0 - q * DIMC;
    const unsigned qoff = (unsigned)(((q & 1) * 28 + ((q >> 1) & 1)) * DIMC);
#pragma unroll
    for (int h = 0; h < 2; ++h) {
      const int koff = h * 32 + quad * 8;    // lane's 8-elem k chunk
      const unsigned a0 = xoff[0] + qoff + (unsigned)(cb + koff);
      const unsigned a1 = xoff[1] + qoff + (unsigned)(cb + koff);
      // Issue all 12 loads up front (independent), then pack, then 16 MFMA.
      float4 a0l = *reinterpret_cast<const float4*>(x + a0);
      float4 a0h = *reinterpret_cast<const float4*>(x + a0 + 4);
      float4 a1l = *reinterpret_cast<const float4*>(x + a1);
      float4 a1h = *reinterpret_cast<const float4*>(x + a1 + 4);
      const unsigned kk = (unsigned)(k0 + koff);
      bf16x8 bf[8];
#pragma unroll
      for (int nt = 0; nt < 8; ++nt)
        bf[nt] = *reinterpret_cast<const bf16x8*>(wbf + boff[nt] + kk);
      bf16x8 af[2];
      af[0] = pack8(a0l, a0h, rs[0], nmu[0]);
      af[1] = pack8(a1l, a1h, rs[1], nmu[1]);
#pragma unroll
      for (int nt = 0; nt < 8; ++nt) {
        acc[0][nt] = __builtin_amdgcn_mfma_f32_16x16x32_bf16(af[0], bf[nt],
                                                             acc[0][nt], 0, 0, 0);
        acc[1][nt] = __builtin_amdgcn_mfma_f32_16x16x32_bf16(af[1], bf[nt],
                                                             acc[1][nt], 0, 0, 0);
      }
    }
  }

  // Epilogue. C/D: col = ln15, row = quad*4 + reg  [m89/m91].
  float bs[8];
#pragma unroll
  for (int nt = 0; nt < 8; ++nt) bs[nt] = bias[cbase + nt * 16 + ln15];
#pragma unroll
  for (int mt = 0; mt < 2; ++mt) {
#pragma unroll
    for (int r = 0; r < 4; ++r) {
      int row = rbase + mt * 16 + quad * 4 + r;
      int b = row / NPATCH;
      int n = row - b * NPATCH;
      float* orow = out + ((size_t)b * 197 + 1 + n) * ODIM + cbase;
#pragma unroll
      for (int nt = 0; nt < 8; ++nt)
        orow[nt * 16 + ln15] = acc[mt][nt][r] + bs[nt];
    }
  }
}

extern "C" void kernel_launch(void* const* d_in, const int* in_sizes, int n_in,
                              void* d_out, int out_size, void* d_ws, size_t ws_size,
                              hipStream_t stream) {
  const float* x     = (const float*)d_in[0];   // (64, 785, 384)
  const float* wred  = (const float*)d_in[1];   // (768, 1536)
  const float* wconv = (const float*)d_in[2];   // (768, 384)
  const float* gamma = (const float*)d_in[3];   // (1536,)
  const float* beta  = (const float*)d_in[4];   // (1536,)
  float* out = (float*)d_out;                   // (64, 197, 768)

  float* stats        = (float*)d_ws;
  unsigned short* wbf = (unsigned short*)((char*)d_ws + WS_WBF_OFF);
  float* bias         = (float*)((char*)d_ws + WS_BIAS_OFF);

  prep_kernel<<<dim3(4672), 256, 0, stream>>>(x, wred, wconv, gamma, beta,
                                              stats, wbf, bias, out);
  gemm_kernel<<<dim3(588), 256, 0, stream>>>(x, wbf, stats, bias, out);
}

// Round 3
// 205.378 us; speedup vs baseline: 2.2701x; 1.7821x over previous
//
#include <hip/hip_runtime.h>
#include <hip/hip_bf16.h>

#define DIMC 384          // C
#define LL 785            // 1 + 28*28
#define FDIM 1536         // 4*C  (GEMM K)
#define ODIM 768          // 2*C  (GEMM N)
#define NPATCH 196        // 14*14
#define MROWS 12544       // B*196 (GEMM M)
#define BATCH 64

typedef __attribute__((ext_vector_type(8))) short bf16x8;
typedef __attribute__((ext_vector_type(4))) float floatx4;
typedef __attribute__((ext_vector_type(4))) unsigned short ushort4v;

// ws layout (bytes):
//   anorm u16[12544*1536] @ 0           (38,535,168 B)  pre-normalized bf16 A
//   wbf   u16[768*1536]   @ 38535168    ( 2,359,296 B)  bf16(gamma * w_red)
//   bias  f32[768]        @ 40894464    (     3,072 B)  sum_f beta*w_red
// total 40,897,536 B (~39 MB)
#define WS_WBF_OFF  38535168
#define WS_BIAS_OFF 40894464

__device__ __forceinline__ unsigned short f2bf(float f) {
  union { float f; unsigned int u; } v; v.f = f;
  unsigned int u = v.u + 0x7fffu + ((v.u >> 16) & 1u);   // RNE
  return (unsigned short)(u >> 16);
}

__device__ __forceinline__ void gload_lds16(const void* g, void* l) {
  __builtin_amdgcn_global_load_lds(
      (const __attribute__((address_space(1))) unsigned int*)g,
      (__attribute__((address_space(3))) unsigned int*)l, 16, 0, 0);
}

// ---------------------------------------------------------------------------
// Prep kernel (one launch, block ranges by role):
//  [0,3136)      norm: one wave per m-row. Gather 1536 floats (24/lane),
//                wave-reduce mu/var, normalize in-register, write bf16 A row.
//                x is read exactly ONCE by this kernel.
//  [3136,4288)   wbf:  wbf[o][f] = bf16(gamma[f] * w_red[o][f])
//  [4288,4480)   bias: bias[o] = sum_f beta[f] * w_red[o][f]
//  [4480,4672)   cls:  out[b,0,o] = dot(x[b,0,:], w_conv[o,:])
// ---------------------------------------------------------------------------
__global__ __launch_bounds__(256) void prep_kernel(
    const float* __restrict__ x, const float* __restrict__ wred,
    const float* __restrict__ wconv, const float* __restrict__ gamma,
    const float* __restrict__ beta, unsigned short* __restrict__ anorm,
    unsigned short* __restrict__ wbf, float* __restrict__ bias,
    float* __restrict__ out) {
  const int blk = blockIdx.x;
  const int t = threadIdx.x;
  const int wv = t >> 6;
  const int lane = t & 63;

  if (blk < 3136) {                      // ---- norm ----
    int gw = blk * 4 + wv;               // m-row
    int b = gw / NPATCH;
    int n = gw - b * NPATCH;
    int i = n / 14;
    int j = n - i * 14;
    const float* xb = x + ((size_t)b * LL + 1) * DIMC;
    float4 v[6];
    float s = 0.f, s2 = 0.f;
#pragma unroll
    for (int c = 0; c < 6; ++c) {
      int f = lane * 4 + c * 256;        // 384%4==0: float4 never crosses q
      int q = f / 384;
      int cc = f - q * 384;
      int off = ((i * 2 + (q & 1)) * 28 + (j * 2 + ((q >> 1) & 1))) * DIMC + cc;
      v[c] = *reinterpret_cast<const float4*>(xb + off);
      s  += v[c].x + v[c].y + v[c].z + v[c].w;
      s2 += v[c].x * v[c].x + v[c].y * v[c].y + v[c].z * v[c].z + v[c].w * v[c].w;
    }
#pragma unroll
    for (int o = 1; o < 64; o <<= 1) {   // butterfly: all lanes get the sums
      s  += __shfl_xor(s, o);
      s2 += __shfl_xor(s2, o);
    }
    float mu = s * (1.f / FDIM);
    float var = s2 * (1.f / FDIM) - mu * mu;
    float rs = rsqrtf(var + 1e-5f);
    float nmu = -mu * rs;                // a = v*rs + nmu
    unsigned short* arow = anorm + (size_t)gw * FDIM;
#pragma unroll
    for (int c = 0; c < 6; ++c) {
      int f = lane * 4 + c * 256;
      union { ushort4v u4; __hip_bfloat162 h[2]; } u;
      u.h[0] = __float22bfloat162_rn(
          make_float2(v[c].x * rs + nmu, v[c].y * rs + nmu));
      u.h[1] = __float22bfloat162_rn(
          make_float2(v[c].z * rs + nmu, v[c].w * rs + nmu));
      *reinterpret_cast<ushort4v*>(arow + f) = u.u4;
    }
  } else if (blk < 4288) {               // ---- wbf = bf16(gamma * w_red) ----
    int idx4 = (blk - 3136) * 256 + t;   // < 294912
    int e0 = idx4 * 4;
    int f = e0 % FDIM;                   // float4 stays in-row (1536%4==0)
    float4 w = *reinterpret_cast<const float4*>(wred + e0);
    float4 g = *reinterpret_cast<const float4*>(gamma + f);
    ushort4v u;
    u.x = f2bf(w.x * g.x); u.y = f2bf(w.y * g.y);
    u.z = f2bf(w.z * g.z); u.w = f2bf(w.w * g.w);
    *reinterpret_cast<ushort4v*>(wbf + e0) = u;
  } else if (blk < 4480) {               // ---- bias ----
    int o = (blk - 4288) * 4 + wv;       // < 768
    const float* wr = wred + (size_t)o * FDIM;
    float s = 0.f;
#pragma unroll
    for (int c = 0; c < 6; ++c) {
      int f = lane * 4 + c * 256;
      float4 w = *reinterpret_cast<const float4*>(wr + f);
      float4 be = *reinterpret_cast<const float4*>(beta + f);
      s += w.x * be.x + w.y * be.y + w.z * be.z + w.w * be.w;
    }
#pragma unroll
    for (int o2 = 32; o2 > 0; o2 >>= 1) s += __shfl_down(s, o2);
    if (lane == 0) bias[o] = s;
  } else {                               // ---- cls ----
    __shared__ float xs[DIMC];
    int idx = blk - 4480;                // < 192
    int b = idx / 3;
    int ch = idx - b * 3;
    for (int c = t; c < DIMC; c += 256) xs[c] = x[(size_t)b * LL * DIMC + c];
    __syncthreads();
    int o = ch * 256 + t;
    const float* wr = wconv + (size_t)o * DIMC;
    float acc = 0.f;
#pragma unroll 4
    for (int c = 0; c < DIMC; c += 4) {
      float4 w = *reinterpret_cast<const float4*>(wr + c);
      acc += w.x * xs[c] + w.y * xs[c + 1] + w.z * xs[c + 2] + w.w * xs[c + 3];
    }
    out[(size_t)b * 197 * ODIM + o] = acc;
  }
}

// ---------------------------------------------------------------------------
// GEMM (m97 structure): C[m,o] = sum_f anorm[m,f] * wbf[o,f] + bias[o].
// Both operands bf16, K-contiguous. Tile 128x128, BK=64, 256 thr = 4 waves
// in 2x2, each wave 64x64 = 4x4 of 16x16x32 MFMA.
// Staging: global_load_lds width=16 (8 per thread per BK). LDS chunks are
// XOR-swizzled: slot (r, c) holds global k-chunk c^(r&7) so fragment
// ds_read_b128 hits 8 distinct bank groups per 8 rows (2-way only = free).
// ---------------------------------------------------------------------------
__global__ __launch_bounds__(256) void gemm_kernel(
    const unsigned short* __restrict__ anorm,
    const unsigned short* __restrict__ wbf,
    const float* __restrict__ bias, float* __restrict__ out) {
  __shared__ unsigned short As[128 * 64];   // 16 KB
  __shared__ unsigned short Bs[128 * 64];   // 16 KB

  const int t = threadIdx.x;
  const int mBase = blockIdx.y * 128;
  const int nBase = blockIdx.x * 128;

  // Staging precompute: slot s = p*256+t -> row r=s>>3, chunk c0=s&7;
  // source chunk cs = c0 ^ (r&7); LDS dest = s*16 bytes (= base + lane*16).
  const unsigned short* agp[4];
  const unsigned short* bgp[4];
  unsigned int ldsoff[4];
#pragma unroll
  for (int p = 0; p < 4; ++p) {
    int s = p * 256 + t;
    int r = s >> 3;
    int cs = (s & 7) ^ (r & 7);
    agp[p] = anorm + (size_t)(mBase + r) * FDIM + cs * 8;
    bgp[p] = wbf + (size_t)(nBase + r) * FDIM + cs * 8;
    ldsoff[p] = (unsigned)s * 8;
  }

  const int wv = t >> 6;
  const int lane = t & 63;
  const int ln15 = lane & 15;
  const int quad = lane >> 4;
  const int wm = wv >> 1;
  const int wn = wv & 1;

  // Fragment LDS element offsets (fixed across the K loop).
  unsigned int aoff[4][2], boff[4][2];
#pragma unroll
  for (int mt = 0; mt < 4; ++mt) {
#pragma unroll
    for (int h = 0; h < 2; ++h) {
      int rA = wm * 64 + mt * 16 + ln15;
      aoff[mt][h] = (unsigned)(rA * 64 + (((h * 4 + quad) ^ (rA & 7)) * 8));
      int rB = wn * 64 + mt * 16 + ln15;
      boff[mt][h] = (unsigned)(rB * 64 + (((h * 4 + quad) ^ (rB & 7)) * 8));
    }
  }

  floatx4 acc[4][4];
#pragma unroll
  for (int mt = 0; mt < 4; ++mt)
#pragma unroll
    for (int nt = 0; nt < 4; ++nt)
      acc[mt][nt] = floatx4{0.f, 0.f, 0.f, 0.f};

  for (int kt = 0; kt < FDIM / 64; ++kt) {
    if (kt) __syncthreads();             // all waves done reading prev tile
#pragma unroll
    for (int p = 0; p < 4; ++p) {
      gload_lds16(agp[p], &As[ldsoff[p]]);
      gload_lds16(bgp[p], &Bs[ldsoff[p]]);
      agp[p] += 64;
      bgp[p] += 64;
    }
    __syncthreads();                     // compiler adds vmcnt(0) drain

#pragma unroll
    for (int h = 0; h < 2; ++h) {
      bf16x8 af[4], bfr[4];
#pragma unroll
      for (int mt = 0; mt < 4; ++mt)
        af[mt] = *reinterpret_cast<const bf16x8*>(&As[aoff[mt][h]]);
#pragma unroll
      for (int nt = 0; nt < 4; ++nt)
        bfr[nt] = *reinterpret_cast<const bf16x8*>(&Bs[boff[nt][h]]);
#pragma unroll
      for (int mt = 0; mt < 4; ++mt)
#pragma unroll
        for (int nt = 0; nt < 4; ++nt)
          acc[mt][nt] = __builtin_amdgcn_mfma_f32_16x16x32_bf16(
              af[mt], bfr[nt], acc[mt][nt], 0, 0, 0);
    }
  }

  // Epilogue. C/D: col = ln15, row = quad*4 + reg  [m89/m91].
  float bs[4];
#pragma unroll
  for (int nt = 0; nt < 4; ++nt)
    bs[nt] = bias[nBase + wn * 64 + nt * 16 + ln15];
#pragma unroll
  for (int mt = 0; mt < 4; ++mt) {
#pragma unroll
    for (int r = 0; r < 4; ++r) {
      int m = mBase + wm * 64 + mt * 16 + quad * 4 + r;
      int b = m / NPATCH;
      int n = m - b * NPATCH;
      float* orow = out + ((size_t)b * 197 + 1 + n) * ODIM + nBase + wn * 64;
#pragma unroll
      for (int nt = 0; nt < 4; ++nt)
        orow[nt * 16 + ln15] = acc[mt][nt][r] + bs[nt];
    }
  }
}

extern "C" void kernel_launch(void* const* d_in, const int* in_sizes, int n_in,
                              void* d_out, int out_size, void* d_ws, size_t ws_size,
                              hipStream_t stream) {
  const float* x     = (const float*)d_in[0];   // (64, 785, 384)
  const float* wred  = (const float*)d_in[1];   // (768, 1536)
  const float* wconv = (const float*)d_in[2];   // (768, 384)
  const float* gamma = (const float*)d_in[3];   // (1536,)
  const float* beta  = (const float*)d_in[4];   // (1536,)
  float* out = (float*)d_out;                   // (64, 197, 768)

  unsigned short* anorm = (unsigned short*)d_ws;
  unsigned short* wbf   = (unsigned short*)((char*)d_ws + WS_WBF_OFF);
  float* bias           = (float*)((char*)d_ws + WS_BIAS_OFF);

  prep_kernel<<<dim3(4672), 256, 0, stream>>>(x, wred, wconv, gamma, beta,
                                              anorm, wbf, bias, out);
  gemm_kernel<<<dim3(ODIM / 128, MROWS / 128), 256, 0, stream>>>(anorm, wbf,
                                                                 bias, out);
}